// Round 11
// baseline (264.483 us; speedup 1.0000x reference)
//
#include <hip/hip_runtime.h>

// LocalL1Loss: out = mean_{n,h,w} min_{7x7 shift} mean_c |in - shifted(tgt, zero-pad)|
// inputs/targets: (16, 3, 512, 512) fp32. Output: scalar fp32.
// R10: persistent 2-tile blocks + double-buffered LDS. Stage(tile1)+input
// loads issue before eval(tile0) -> tile1 memory latency hides under eval.
// Grid 1024 = 4 blocks/CU, single generation (kills convoy + phase-serialize).
// Eval/staging bodies = R4 (best known). Spill tripwire: WRITE_SIZE.

constexpr int N = 16, C = 3, H = 512, W = 512;
constexpr int K = 7, HALO = 3;
constexpr int TH = 32, TW = 64;          // per-tile output block
constexpr int TILES = 2;                 // vertical tiles per block
constexpr int SM_ROWS = TH + 2 * HALO;   // 38
constexpr int SM_D = 36;                 // dwords/row: halves [w0-4 .. w0+67]
constexpr int BUF = C * SM_ROWS * SM_D;  // 4104 dwords per buffer
constexpr int BLK = 256;                 // 32 rows x 8 strips of 8 = 4 waves

typedef _Float16 h2 __attribute__((ext_vector_type(2)));
__device__ inline h2 u2h(unsigned u) { return __builtin_bit_cast(h2, u); }
__device__ inline h2 habs2(h2 x) {
    unsigned u = __builtin_bit_cast(unsigned, x) & 0x7fff7fffu;
    return __builtin_bit_cast(h2, u);
}

// stage one 38-row x 72-half tile (3 channels) into buf as packed f16
__device__ __forceinline__ void stage_tile(const float* tbase, unsigned* buf,
                                           int h0, int w0, int tid) {
    const bool interior = (h0 != 0) && (h0 != H - TH) && (w0 != 0) && (w0 != W - TW);
    int rr = tid / SM_D;
    int d2 = tid - rr * SM_D;
    int r  = rr;                      // c=0 for tid<256
    int c  = 0;
    const int f2base = w0 / 2 - 2;    // float2 index of d2=0
    #pragma unroll
    for (int it = 0; it < 17; ++it) {
        if (it < 16 || tid < 8) {     // TOTAL 4104 = 16*256 + 8
            const int gr = h0 + r - HALO;
            unsigned val;
            if (interior) {
                const float2* rowp = reinterpret_cast<const float2*>(
                    tbase + ((size_t)c * H + gr) * W);
                float2 v2 = rowp[f2base + d2];
                h2 v; v[0] = (_Float16)v2.x; v[1] = (_Float16)v2.y;
                val = __builtin_bit_cast(unsigned, v);
            } else {
                const int gc = w0 - 4 + 2 * d2;
                float f0 = 0.0f, f1 = 0.0f;
                if ((unsigned)gr < (unsigned)H) {
                    const float* rowp = tbase + ((size_t)c * H + gr) * W;
                    if ((unsigned)gc       < (unsigned)W) f0 = rowp[gc];
                    if ((unsigned)(gc + 1) < (unsigned)W) f1 = rowp[gc + 1];
                }
                h2 v; v[0] = (_Float16)f0; v[1] = (_Float16)f1;
                val = __builtin_bit_cast(unsigned, v);
            }
            buf[rr * SM_D + d2] = val;
        }
        rr += 7; r += 7; d2 += 4;                  // step 256 = 7*36 + 4
        if (d2 >= SM_D) { d2 -= SM_D; rr += 1; r += 1; }
        if (r >= SM_ROWS) { r -= SM_ROWS; c += 1; }
    }
}

__device__ __forceinline__ void load_inputs(const float* inputs, int n, int h,
                                            int wb, float4 ia[3], float4 ib[3]) {
    const float* ibase = inputs + ((size_t)n * C * H + (size_t)h) * W + wb;
    #pragma unroll
    for (int c = 0; c < 3; ++c) {
        ia[c] = *reinterpret_cast<const float4*>(ibase + (size_t)c * H * W);
        ib[c] = *reinterpret_cast<const float4*>(ibase + (size_t)c * H * W + 4);
    }
}

__device__ __forceinline__ void cvt_inputs(const float4 ia[3], const float4 ib[3],
                                           h2 ipk[3][4]) {
    #pragma unroll
    for (int c = 0; c < 3; ++c) {
        ipk[c][0][0] = (_Float16)ia[c].x; ipk[c][0][1] = (_Float16)ia[c].y;
        ipk[c][1][0] = (_Float16)ia[c].z; ipk[c][1][1] = (_Float16)ia[c].w;
        ipk[c][2][0] = (_Float16)ib[c].x; ipk[c][2][1] = (_Float16)ib[c].y;
        ipk[c][3][0] = (_Float16)ib[c].z; ipk[c][3][1] = (_Float16)ib[c].w;
    }
}

// evaluate one 32x64 tile against staged buffer; accumulate sum of per-pixel min
__device__ __forceinline__ void eval_tile(const unsigned* buf, const h2 ipk[3][4],
                                          int ty, int tx, float& part) {
    h2 bestA[4], bestB[4];
    #pragma unroll
    for (int p = 0; p < 4; ++p) { bestA[p] = u2h(0x7bff7bffu); bestB[p] = u2h(0x7bff7bffu); }

    #pragma unroll
    for (int di = 0; di < K; ++di) {
        unsigned t2[3][8];
        #pragma unroll
        for (int c = 0; c < 3; ++c) {
            const uint4* q = reinterpret_cast<const uint4*>(
                &buf[(c * SM_ROWS + (ty + di)) * SM_D + tx * 4]);
            uint4 lo = q[0], hi = q[1];
            t2[c][0] = lo.x; t2[c][1] = lo.y; t2[c][2] = lo.z; t2[c][3] = lo.w;
            t2[c][4] = hi.x; t2[c][5] = hi.y; t2[c][6] = hi.z; t2[c][7] = hi.w;
        }
        unsigned s[3][7];
        #pragma unroll
        for (int c = 0; c < 3; ++c)
            #pragma unroll
            for (int m = 0; m < 7; ++m)
                s[c][m] = __builtin_amdgcn_alignbit(t2[c][m + 1], t2[c][m], 16);

        #pragma unroll
        for (int dj = 0; dj < K; ++dj) {
            #pragma unroll
            for (int p = 0; p < 4; ++p) {
                h2 w0h, w1h, w2h;
                if (dj & 1) {
                    const int m = p + (dj + 1) / 2;
                    w0h = u2h(t2[0][m]); w1h = u2h(t2[1][m]); w2h = u2h(t2[2][m]);
                } else {
                    const int m = p + dj / 2;
                    w0h = u2h(s[0][m]); w1h = u2h(s[1][m]); w2h = u2h(s[2][m]);
                }
                h2 a0 = habs2(ipk[0][p] - w0h);
                h2 a1 = habs2(ipk[1][p] - w1h);
                h2 a2 = habs2(ipk[2][p] - w2h);
                h2 d  = a0 + a1 + a2;
                if (dj & 1) bestB[p] = __builtin_elementwise_min(bestB[p], d);
                else        bestA[p] = __builtin_elementwise_min(bestA[p], d);
            }
        }
    }
    #pragma unroll
    for (int p = 0; p < 4; ++p) {
        h2 b = __builtin_elementwise_min(bestA[p], bestB[p]);
        part += (float)b[0] + (float)b[1];
    }
}

__global__ __launch_bounds__(BLK, 4)
void local_l1_kernel(const float* __restrict__ inputs,
                     const float* __restrict__ targets,
                     float* __restrict__ out) {
    __shared__ unsigned sm_u[2 * BUF];   // 32,832 B -> 4 blocks/CU

    const int tid = threadIdx.x;
    const int w0 = blockIdx.x * TW;
    const int h0 = blockIdx.y * (TILES * TH);    // tiles at h0, h0+TH
    const int n  = blockIdx.z;

    const int tx = tid & 7;
    const int ty = tid >> 3;
    const int wb = w0 + tx * 8;
    const float* tbase = targets + (size_t)n * C * H * W;

    // ---- prologue: tile0 inputs + staging ----
    float4 ia[3], ib[3];
    load_inputs(inputs, n, h0 + ty, wb, ia, ib);
    stage_tile(tbase, sm_u, h0, w0, tid);
    h2 ipk0[3][4];
    cvt_inputs(ia, ib, ipk0);
    __syncthreads();

    float part = 0.0f;

    // ---- iteration: prep tile1 (loads hide under eval0), eval tile0 ----
    load_inputs(inputs, n, h0 + TH + ty, wb, ia, ib);
    stage_tile(tbase, sm_u + BUF, h0 + TH, w0, tid);
    h2 ipk1[3][4];
    cvt_inputs(ia, ib, ipk1);

    eval_tile(sm_u, ipk0, ty, tx, part);
    __syncthreads();

    eval_tile(sm_u + BUF, ipk1, ty, tx, part);

    // ---- reduction ----
    #pragma unroll
    for (int off = 32; off > 0; off >>= 1)
        part += __shfl_down(part, off, 64);

    __shared__ float wsum[BLK / 64];
    if ((tid & 63) == 0) wsum[tid >> 6] = part;
    __syncthreads();
    if (tid == 0) {
        float total = 0.0f;
        #pragma unroll
        for (int i = 0; i < BLK / 64; ++i) total += wsum[i];
        atomicAdd(out, total * (1.0f / (3.0f * (float)N * (float)H * (float)W)));
    }
}

extern "C" void kernel_launch(void* const* d_in, const int* in_sizes, int n_in,
                              void* d_out, int out_size, void* d_ws, size_t ws_size,
                              hipStream_t stream) {
    const float* inputs  = (const float*)d_in[0];
    const float* targets = (const float*)d_in[1];
    float* out = (float*)d_out;

    (void)hipMemsetAsync(out, 0, sizeof(float), stream);
    dim3 grid(W / TW, H / (TILES * TH), N);
    local_l1_kernel<<<grid, BLK, 0, stream>>>(inputs, targets, out);
}

// Round 12
// 77.827 us; speedup vs baseline: 3.3984x; 3.3984x over previous
//
#include <hip/hip_runtime.h>

// LocalL1Loss: out = mean_{n,h,w} min_{7x7 shift} mean_c |in - shifted(tgt, zero-pad)|
// inputs/targets: (16, 3, 512, 512) fp32. Output: scalar fp32.
// R11: NO LDS staging, NO barrier (except final reduce). Targets read directly
// from global as aligned float4 (L1/L2 serve the 7x vertical reuse), packed to
// f16 via v_cvt_pkrtz_f16_f32 (replaces alignbit). Eval = proven packed form.
// R8/R10 lesson: keep live state small; WRITE_SIZE is the spill tripwire.

constexpr int N = 16, C = 3, H = 512, W = 512;
constexpr int K = 7;
constexpr int TH = 32, TW = 64;          // output tile per block
constexpr int BLK = 256;                 // 32 rows x 8 strips of 8

typedef _Float16 h2 __attribute__((ext_vector_type(2)));
__device__ inline h2 u2h(unsigned u) { return __builtin_bit_cast(h2, u); }
__device__ inline h2 habs2(h2 x) {
    unsigned u = __builtin_bit_cast(unsigned, x) & 0x7fff7fffu;
    return __builtin_bit_cast(h2, u);
}
__device__ inline unsigned pkrtz(float a, float b) {
    return __builtin_bit_cast(unsigned, __builtin_amdgcn_cvt_pkrtz(a, b));
}

// eval one target row (q = even-start pairs, s = odd-start pairs) vs inputs
__device__ __forceinline__ void eval_row(const h2 ipk[3][4],
                                         const unsigned q[3][8],
                                         const unsigned s[3][7],
                                         h2 bestA[4], h2 bestB[4]) {
    #pragma unroll
    for (int dj = 0; dj < K; ++dj) {
        #pragma unroll
        for (int p = 0; p < 4; ++p) {
            h2 w0h, w1h, w2h;
            if (dj & 1) {          // even half-offset -> q
                const int m = p + (dj + 1) / 2;
                w0h = u2h(q[0][m]); w1h = u2h(q[1][m]); w2h = u2h(q[2][m]);
            } else {               // odd half-offset -> s
                const int m = p + dj / 2;
                w0h = u2h(s[0][m]); w1h = u2h(s[1][m]); w2h = u2h(s[2][m]);
            }
            h2 a0 = habs2(ipk[0][p] - w0h);
            h2 a1 = habs2(ipk[1][p] - w1h);
            h2 a2 = habs2(ipk[2][p] - w2h);
            h2 d  = a0 + a1 + a2;
            if (dj & 1) bestB[p] = __builtin_elementwise_min(bestB[p], d);
            else        bestA[p] = __builtin_elementwise_min(bestA[p], d);
        }
    }
}

__global__ __launch_bounds__(BLK)
void local_l1_kernel(const float* __restrict__ inputs,
                     const float* __restrict__ targets,
                     float* __restrict__ out) {
    const int tid = threadIdx.x;
    const int tx = tid & 7;    // strip (8 outputs wide)
    const int ty = tid >> 3;   // row in tile
    const int w0 = blockIdx.x * TW;
    const int h0 = blockIdx.y * TH;
    const int n  = blockIdx.z;

    const int wb = w0 + tx * 8;     // first output col
    const int cb = wb - 4;          // first loaded col (16 floats cb..cb+15)
    const int hr = h0 + ty;         // output row

    // ---- inputs: 3ch x 8, convert to 4 packed pairs ----
    const float* ibase = inputs + ((size_t)n * C * H + (size_t)hr) * W + wb;
    h2 ipk[3][4];
    #pragma unroll
    for (int c = 0; c < 3; ++c) {
        float4 a = *reinterpret_cast<const float4*>(ibase + (size_t)c * H * W);
        float4 b = *reinterpret_cast<const float4*>(ibase + (size_t)c * H * W + 4);
        ipk[c][0] = u2h(pkrtz(a.x, a.y));
        ipk[c][1] = u2h(pkrtz(a.z, a.w));
        ipk[c][2] = u2h(pkrtz(b.x, b.y));
        ipk[c][3] = u2h(pkrtz(b.z, b.w));
    }

    h2 bestA[4], bestB[4];
    #pragma unroll
    for (int p = 0; p < 4; ++p) { bestA[p] = u2h(0x7bff7bffu); bestB[p] = u2h(0x7bff7bffu); }

    const float* tbase = targets + (size_t)n * C * H * W;
    const bool safe = (hr >= 3) && (hr <= H - 4) && (cb >= 0) && (cb + 16 <= W);

    if (safe) {
        // ---- fast path: all 7 rows x 16 cols in bounds ----
        #pragma unroll
        for (int di = 0; di < K; ++di) {
            const float* rp = tbase + (size_t)(hr + di - 3) * W + cb;
            unsigned q[3][8], s[3][7];
            #pragma unroll
            for (int c = 0; c < 3; ++c) {
                float fr[16];
                #pragma unroll
                for (int j = 0; j < 4; ++j)
                    *reinterpret_cast<float4*>(&fr[4 * j]) =
                        *reinterpret_cast<const float4*>(rp + (size_t)c * H * W + 4 * j);
                #pragma unroll
                for (int m = 0; m < 8; ++m) q[c][m] = pkrtz(fr[2 * m], fr[2 * m + 1]);
                #pragma unroll
                for (int m = 0; m < 7; ++m) s[c][m] = pkrtz(fr[2 * m + 1], fr[2 * m + 2]);
            }
            eval_row(ipk, q, s, bestA, bestB);
        }
    } else {
        // ---- edge path: per-float4 bounds check (float4 granularity holds:
        // cb is a multiple of 4 and W=512) ----
        #pragma unroll
        for (int di = 0; di < K; ++di) {
            const int gr = hr + di - 3;
            const bool rowOK = (unsigned)gr < (unsigned)H;
            const float* rp = tbase + (size_t)(rowOK ? gr : 0) * W;
            unsigned q[3][8], s[3][7];
            #pragma unroll
            for (int c = 0; c < 3; ++c) {
                float fr[16];
                #pragma unroll
                for (int j = 0; j < 4; ++j) {
                    const int c4 = cb + 4 * j;
                    const bool ok = rowOK && c4 >= 0 && c4 + 4 <= W;
                    const int cc = c4 < 0 ? 0 : (c4 > W - 4 ? W - 4 : c4);
                    float4 v = *reinterpret_cast<const float4*>(rp + (size_t)c * H * W + cc);
                    if (!ok) { v.x = 0.f; v.y = 0.f; v.z = 0.f; v.w = 0.f; }
                    *reinterpret_cast<float4*>(&fr[4 * j]) = v;
                }
                #pragma unroll
                for (int m = 0; m < 8; ++m) q[c][m] = pkrtz(fr[2 * m], fr[2 * m + 1]);
                #pragma unroll
                for (int m = 0; m < 7; ++m) s[c][m] = pkrtz(fr[2 * m + 1], fr[2 * m + 2]);
            }
            eval_row(ipk, q, s, bestA, bestB);
        }
    }

    float part = 0.0f;
    #pragma unroll
    for (int p = 0; p < 4; ++p) {
        h2 b = __builtin_elementwise_min(bestA[p], bestB[p]);
        part += (float)b[0] + (float)b[1];
    }

    // wave reduction, then cross-wave via (tiny) LDS
    #pragma unroll
    for (int off = 32; off > 0; off >>= 1)
        part += __shfl_down(part, off, 64);

    __shared__ float wsum[BLK / 64];
    if ((tid & 63) == 0) wsum[tid >> 6] = part;
    __syncthreads();
    if (tid == 0) {
        float total = 0.0f;
        #pragma unroll
        for (int i = 0; i < BLK / 64; ++i) total += wsum[i];
        atomicAdd(out, total * (1.0f / (3.0f * (float)N * (float)H * (float)W)));
    }
}

extern "C" void kernel_launch(void* const* d_in, const int* in_sizes, int n_in,
                              void* d_out, int out_size, void* d_ws, size_t ws_size,
                              hipStream_t stream) {
    const float* inputs  = (const float*)d_in[0];
    const float* targets = (const float*)d_in[1];
    float* out = (float*)d_out;

    (void)hipMemsetAsync(out, 0, sizeof(float), stream);
    dim3 grid(W / TW, H / TH, N);
    local_l1_kernel<<<grid, BLK, 0, stream>>>(inputs, targets, out);
}

// Round 13
// 56.312 us; speedup vs baseline: 4.6968x; 1.3821x over previous
//
#include <hip/hip_runtime.h>

// LocalL1Loss: out = mean_{n,h,w} min_{7x7 shift} mean_c |in - shifted(tgt, zero-pad)|
// inputs/targets: (16, 3, 512, 512) fp32. Output: scalar fp32.
// R12: single-generation grid (64x64 tile, BLK=512 -> 1024 blocks = 4/CU x 8
// waves = full residency in ONE generation) + 4-deep batched staging loads
// (at 32 VGPR the 17-step stage chain was load-use serialized; batch of 4
// independent float2 loads before cvt+write restores MLP). Eval body = R4.

constexpr int N = 16, C = 3, H = 512, W = 512;
constexpr int K = 7, HALO = 3;
constexpr int TH = 64, TW = 64;          // output tile per block
constexpr int SM_ROWS = TH + 2 * HALO;   // 70
constexpr int SM_D = 36;                 // dwords/row: halves [w0-4 .. w0+67]
constexpr int BLK = 512;                 // 64 rows x 8 strips of 8 = 8 waves
constexpr int TOTAL = C * SM_ROWS * SM_D;            // 7560 = 14*512 + 392

typedef _Float16 h2 __attribute__((ext_vector_type(2)));
__device__ inline h2 u2h(unsigned u) { return __builtin_bit_cast(h2, u); }
__device__ inline h2 habs2(h2 x) {
    unsigned u = __builtin_bit_cast(unsigned, x) & 0x7fff7fffu;
    return __builtin_bit_cast(h2, u);
}
__device__ inline unsigned f2pk(float a, float b) {
    h2 v; v[0] = (_Float16)a; v[1] = (_Float16)b;
    return __builtin_bit_cast(unsigned, v);
}

__global__ __launch_bounds__(BLK, 8)
void local_l1_kernel(const float* __restrict__ inputs,
                     const float* __restrict__ targets,
                     float* __restrict__ out) {
    __shared__ unsigned sm_u[TOTAL];     // 30,240 B -> 4 blocks/CU (wave cap)

    const int tid = threadIdx.x;
    const int w0 = blockIdx.x * TW;
    const int h0 = blockIdx.y * TH;
    const int n  = blockIdx.z;

    const int tx = tid & 7;    // strip index (w)
    const int ty = tid >> 3;   // row in tile (0..63)

    // ---- issue input loads FIRST so they overlap the staging burst ----
    const float* ibase = inputs + ((size_t)n * C * H + (size_t)(h0 + ty)) * W
                       + (w0 + tx * 8);
    float4 ia[3], ib[3];
    #pragma unroll
    for (int c = 0; c < 3; ++c) {
        ia[c] = *reinterpret_cast<const float4*>(ibase + (size_t)c * H * W);
        ib[c] = *reinterpret_cast<const float4*>(ibase + (size_t)c * H * W + 4);
    }

    // ---- stage targets tile into LDS as packed f16, even-parity layout ----
    // flat dword index = (c*70 + r)*36 + d2 ; global float2 = row[f2base + d2]
    const float* tbase = targets + (size_t)n * C * H * W;
    const bool interior = (h0 != 0) && (h0 != H - TH) && (w0 != 0) && (w0 != W - TW);
    {
        int rr = tid / SM_D;              // c*70 + r (c=0 initially: rr<15)
        int d2 = tid - rr * SM_D;
        int r  = rr;
        int c  = 0;
        const int f2base = w0 / 2 - 2;    // float2 index of d2=0

        if (interior) {
            // 14 full iterations as batches of 4/4/4/2, then tail (tid<392)
            #pragma unroll
            for (int g = 0; g < 4; ++g) {
                const int B = (g < 3) ? 4 : 2;
                float2 v[4]; int idx[4];
                #pragma unroll
                for (int b = 0; b < B; ++b) {
                    const int gr = h0 + r - HALO;
                    v[b] = reinterpret_cast<const float2*>(
                        tbase + ((size_t)c * H + gr) * W)[f2base + d2];
                    idx[b] = rr * SM_D + d2;
                    rr += 14; r += 14; d2 += 8;        // step 512 = 14*36 + 8
                    if (d2 >= SM_D) { d2 -= SM_D; rr += 1; r += 1; }
                    if (r >= SM_ROWS) { r -= SM_ROWS; c += 1; }
                }
                #pragma unroll
                for (int b = 0; b < B; ++b)
                    sm_u[idx[b]] = f2pk(v[b].x, v[b].y);
            }
            if (tid < TOTAL - 14 * BLK) {              // tail: 392 threads
                const int gr = h0 + r - HALO;
                float2 v2 = reinterpret_cast<const float2*>(
                    tbase + ((size_t)c * H + gr) * W)[f2base + d2];
                sm_u[rr * SM_D + d2] = f2pk(v2.x, v2.y);
            }
        } else {
            #pragma unroll
            for (int it = 0; it < 15; ++it) {
                if (it < 14 || tid < TOTAL - 14 * BLK) {
                    const int gr = h0 + r - HALO;
                    const int gc = w0 - 4 + 2 * d2;
                    float f0 = 0.0f, f1 = 0.0f;
                    if ((unsigned)gr < (unsigned)H) {
                        const float* rowp = tbase + ((size_t)c * H + gr) * W;
                        if ((unsigned)gc       < (unsigned)W) f0 = rowp[gc];
                        if ((unsigned)(gc + 1) < (unsigned)W) f1 = rowp[gc + 1];
                    }
                    sm_u[rr * SM_D + d2] = f2pk(f0, f1);
                }
                rr += 14; r += 14; d2 += 8;
                if (d2 >= SM_D) { d2 -= SM_D; rr += 1; r += 1; }
                if (r >= SM_ROWS) { r -= SM_ROWS; c += 1; }
            }
        }
    }

    // convert inputs while staging drains
    h2 in_pk[3][4];
    #pragma unroll
    for (int c = 0; c < 3; ++c) {
        in_pk[c][0][0] = (_Float16)ia[c].x; in_pk[c][0][1] = (_Float16)ia[c].y;
        in_pk[c][1][0] = (_Float16)ia[c].z; in_pk[c][1][1] = (_Float16)ia[c].w;
        in_pk[c][2][0] = (_Float16)ib[c].x; in_pk[c][2][1] = (_Float16)ib[c].y;
        in_pk[c][3][0] = (_Float16)ib[c].z; in_pk[c][3][1] = (_Float16)ib[c].w;
    }
    __syncthreads();

    // ---- main loop: 8 outputs/thread, packed pairs, even/odd-dj split ----
    h2 bestA[4], bestB[4];
    #pragma unroll
    for (int p = 0; p < 4; ++p) { bestA[p] = u2h(0x7bff7bffu); bestB[p] = u2h(0x7bff7bffu); }

    #pragma unroll
    for (int di = 0; di < K; ++di) {
        unsigned t2[3][8];
        #pragma unroll
        for (int c = 0; c < 3; ++c) {
            const uint4* q = reinterpret_cast<const uint4*>(
                &sm_u[(c * SM_ROWS + (ty + di)) * SM_D + tx * 4]);
            uint4 lo = q[0], hi = q[1];
            t2[c][0] = lo.x; t2[c][1] = lo.y; t2[c][2] = lo.z; t2[c][3] = lo.w;
            t2[c][4] = hi.x; t2[c][5] = hi.y; t2[c][6] = hi.z; t2[c][7] = hi.w;
        }
        unsigned s[3][7];
        #pragma unroll
        for (int c = 0; c < 3; ++c)
            #pragma unroll
            for (int m = 0; m < 7; ++m)
                s[c][m] = __builtin_amdgcn_alignbit(t2[c][m + 1], t2[c][m], 16);

        #pragma unroll
        for (int dj = 0; dj < K; ++dj) {
            #pragma unroll
            for (int p = 0; p < 4; ++p) {
                h2 w0h, w1h, w2h;
                if (dj & 1) {
                    const int m = p + (dj + 1) / 2;
                    w0h = u2h(t2[0][m]); w1h = u2h(t2[1][m]); w2h = u2h(t2[2][m]);
                } else {
                    const int m = p + dj / 2;
                    w0h = u2h(s[0][m]); w1h = u2h(s[1][m]); w2h = u2h(s[2][m]);
                }
                h2 a0 = habs2(in_pk[0][p] - w0h);
                h2 a1 = habs2(in_pk[1][p] - w1h);
                h2 a2 = habs2(in_pk[2][p] - w2h);
                h2 d  = a0 + a1 + a2;
                if (dj & 1) bestB[p] = __builtin_elementwise_min(bestB[p], d);
                else        bestA[p] = __builtin_elementwise_min(bestA[p], d);
            }
        }
    }

    float part = 0.0f;
    #pragma unroll
    for (int p = 0; p < 4; ++p) {
        h2 b = __builtin_elementwise_min(bestA[p], bestB[p]);
        part += (float)b[0] + (float)b[1];
    }

    // wave (64-lane) reduction, then cross-wave via LDS
    #pragma unroll
    for (int off = 32; off > 0; off >>= 1)
        part += __shfl_down(part, off, 64);

    __shared__ float wsum[BLK / 64];
    if ((tid & 63) == 0) wsum[tid >> 6] = part;
    __syncthreads();
    if (tid == 0) {
        float total = 0.0f;
        #pragma unroll
        for (int i = 0; i < BLK / 64; ++i) total += wsum[i];
        atomicAdd(out, total * (1.0f / (3.0f * (float)N * (float)H * (float)W)));
    }
}

extern "C" void kernel_launch(void* const* d_in, const int* in_sizes, int n_in,
                              void* d_out, int out_size, void* d_ws, size_t ws_size,
                              hipStream_t stream) {
    const float* inputs  = (const float*)d_in[0];
    const float* targets = (const float*)d_in[1];
    float* out = (float*)d_out;

    (void)hipMemsetAsync(out, 0, sizeof(float), stream);
    dim3 grid(W / TW, H / TH, N);
    local_l1_kernel<<<grid, BLK, 0, stream>>>(inputs, targets, out);
}